// Round 2
// baseline (939.914 us; speedup 1.0000x reference)
//
#include <hip/hip_runtime.h>
#include <hip/hip_bf16.h>
#include <math.h>

typedef __attribute__((ext_vector_type(8))) short bf16x8;
typedef __attribute__((ext_vector_type(4))) float f32x4;
typedef __attribute__((ext_vector_type(4))) unsigned short u16x4;

constexpr int Bn = 64;    // dialogues
constexpr int Ln = 512;   // utterances
constexpr int Hd = 768;   // hidden
constexpr int Nn = 50;    // nodes per dialogue
constexpr int On = 768;   // output dim
constexpr int RP = 64;    // padded rows per dialogue (M = Bn*RP = 4096)

constexpr int NBLK = 768;                 // 3 blocks/CU on 256 CUs, all resident
constexpr int AUXW = 5 * Bn * RP;         // zeroed accumulator words

__device__ __forceinline__ f32x4 MFMA(bf16x8 a, bf16x8 b, f32x4 c) {
  return __builtin_amdgcn_mfma_f32_16x16x32_bf16(a, b, c, 0, 0, 0);
}
__device__ __forceinline__ unsigned short f2bb(float v) {
  __hip_bfloat16 h = __float2bfloat16(v);
  return *(unsigned short*)&h;
}

// ===========================================================================
// Single-use full-grid barrier. All NBLK blocks are co-resident by
// construction (launch_bounds(256,3): VGPR<=168 cap, LDS 20.5KB -> 7/CU,
// grid = 3*256 exactly), so arrive-and-poll cannot livelock. Counter zeroed
// by hipMemsetAsync before launch (ws is harness-poisoned every iteration).
__device__ __forceinline__ void grid_bar(int* bar) {
  __syncthreads();
  if (threadIdx.x == 0) {
    __hip_atomic_fetch_add(bar, 1, __ATOMIC_ACQ_REL, __HIP_MEMORY_SCOPE_AGENT);
    while (__hip_atomic_load(bar, __ATOMIC_ACQUIRE, __HIP_MEMORY_SCOPE_AGENT) <
           NBLK) {
      __builtin_amdgcn_s_sleep(4);
    }
  }
  __syncthreads();
}

// ===========================================================================
// Task bodies — verbatim from the proven standalone kernels (R6 lineage),
// __shared__ replaced by the caller's LDS arena. Every task body is
// entered/exited through a __syncthreads() (inside grid_bar), so arena reuse
// across stages is race-free.

// Per-dialogue GEMM tile: C = A[b*64..+64, :] @ Wt^T + bias, 64x64 cols.
// EPI 0: write Wh^T + fused src/dst dots. EPI 1: tanh(C+bias).v into o1.
template <int EPI>
__device__ void gemm_task(char* smemraw, int b, int col0,
                          const __hip_bfloat16* __restrict__ A,
                          const __hip_bfloat16* __restrict__ Bt,
                          const float* __restrict__ bias,
                          __hip_bfloat16* __restrict__ WhT,
                          const float* __restrict__ avec,
                          float* __restrict__ o1, float* __restrict__ o2) {
  typedef __hip_bfloat16 Tile[64][40];
  Tile* As = reinterpret_cast<Tile*>(smemraw);            // [2][64][40]
  Tile* Bs = reinterpret_cast<Tile*>(smemraw + 10240);    // [2][64][40]
  int tid = threadIdx.x;
  int wave = tid >> 6, lane = tid & 63;
  int lr = lane & 15, lq = lane >> 4;
  int row0 = b * RP;
  int sr = tid >> 2, sk = (tid & 3) * 8;
  const __hip_bfloat16* Ap = A + (size_t)(row0 + sr) * Hd + sk;
  const __hip_bfloat16* Bp = Bt + (size_t)(col0 + sr) * Hd + sk;
  uint4 ra = *(const uint4*)Ap;
  uint4 rb = *(const uint4*)Bp;
  *(uint4*)&As[0][sr][sk] = ra;
  *(uint4*)&Bs[0][sr][sk] = rb;
  f32x4 acc[4] = {};
  __syncthreads();
  int cur = 0;
  for (int kt = 32; kt < Hd; kt += 32) {
    ra = *(const uint4*)(Ap + kt);
    rb = *(const uint4*)(Bp + kt);
    bf16x8 af = *(const bf16x8*)&As[cur][wave * 16 + lr][lq * 8];
#pragma unroll
    for (int ct = 0; ct < 4; ++ct)
      acc[ct] = MFMA(af, *(const bf16x8*)&Bs[cur][ct * 16 + lr][lq * 8], acc[ct]);
    *(uint4*)&As[cur ^ 1][sr][sk] = ra;
    *(uint4*)&Bs[cur ^ 1][sr][sk] = rb;
    __syncthreads();
    cur ^= 1;
  }
  {
    bf16x8 af = *(const bf16x8*)&As[cur][wave * 16 + lr][lq * 8];
#pragma unroll
    for (int ct = 0; ct < 4; ++ct)
      acc[ct] = MFMA(af, *(const bf16x8*)&Bs[cur][ct * 16 + lr][lq * 8], acc[ct]);
  }
  int lrow0 = wave * 16 + lq * 4;  // local row base (0..60, mult of 4)
  if (EPI == 0) {
    float ps[4] = {}, pd[4] = {};
#pragma unroll
    for (int ct = 0; ct < 4; ++ct) {
      int gc = col0 + ct * 16 + lr;
      float bv = bias[gc];
      float a_s = avec[gc], a_d = avec[Hd + gc];
      u16x4 pk;
#pragma unroll
      for (int r = 0; r < 4; ++r) {
        float v = acc[ct][r] + bv;
        pk[r] = f2bb(v);
        ps[r] += v * a_s;
        pd[r] += v * a_d;
      }
      *(u16x4*)(WhT + ((size_t)b * Hd + gc) * RP + lrow0) = pk;
    }
#pragma unroll
    for (int off = 8; off; off >>= 1)
#pragma unroll
      for (int r = 0; r < 4; ++r) {
        ps[r] += __shfl_xor(ps[r], off);
        pd[r] += __shfl_xor(pd[r], off);
      }
    if (lr == 0)
#pragma unroll
      for (int r = 0; r < 4; ++r) {
        int row = lrow0 + r;
        if (row < Nn) {
          atomicAdd(&o1[b * RP + row], ps[r]);
          atomicAdd(&o2[b * RP + row], pd[r]);
        }
      }
  } else {
    float pr[4] = {};
#pragma unroll
    for (int ct = 0; ct < 4; ++ct) {
      int gc = col0 + ct * 16 + lr;
      float bv = bias[gc];
      float vv_ = avec[gc];
#pragma unroll
      for (int r = 0; r < 4; ++r) pr[r] += tanhf(acc[ct][r] + bv) * vv_;
    }
#pragma unroll
    for (int off = 8; off; off >>= 1)
#pragma unroll
      for (int r = 0; r < 4; ++r) pr[r] += __shfl_xor(pr[r], off);
    if (lr == 0)
#pragma unroll
      for (int r = 0; r < 4; ++r) {
        int row = lrow0 + r;
        if (row < Nn) atomicAdd(&o1[b * RP + row], pr[r]);
      }
  }
}

// MFMA attention apply for one (dialogue b, col-group cg of 256 cols).
template <int LAYER>
__device__ void attf_task(char* smemraw, int b, int cg,
                          const float* __restrict__ ssrc,
                          const float* __restrict__ sdst,
                          const int* __restrict__ adj,
                          const float* __restrict__ ab,
                          const __hip_bfloat16* __restrict__ WhT,
                          const float* __restrict__ xres,
                          float* __restrict__ hf,
                          __hip_bfloat16* __restrict__ hb) {
  float* attL = reinterpret_cast<float*>(smemraw);                     // Nn*52
  __hip_bfloat16* attB =
      reinterpret_cast<__hip_bfloat16*>(smemraw + Nn * 52 * 4);        // 64*72
  int tid = threadIdx.x;
  float abv = ab[0];
  for (int i = tid; i < 64 * 72; i += 256) attB[i] = __float2bfloat16(0.f);
  for (int idx = tid; idx < Nn * Nn; idx += 256) {
    int i = idx / Nn, j = idx - i * Nn;
    float t = ssrc[b * RP + i] + sdst[b * RP + j] + abv;
    t = t > 0.f ? t : 0.3f * t;  // leaky_relu 0.3
    attL[i * 52 + j] = (adj[(size_t)b * Nn * Nn + idx] > 0) ? t : -9.0e15f;
  }
  __syncthreads();
  if (tid < Nn) {
    float m = -3.0e38f;
    for (int j = 0; j < Nn; ++j) m = fmaxf(m, attL[tid * 52 + j]);
    float s = 0.f;
    for (int j = 0; j < Nn; ++j) {
      float p = expf(attL[tid * 52 + j] - m);
      attL[tid * 52 + j] = p;
      s += p;
    }
    float inv = 1.f / s;
    for (int j = 0; j < Nn; ++j) attL[tid * 52 + j] *= inv;
  }
  __syncthreads();
  for (int idx = tid; idx < Nn * Nn; idx += 256) {
    int i = idx / Nn, j = idx - i * Nn;
    attB[i * 72 + j] = __float2bfloat16(attL[i * 52 + j]);
  }
  __syncthreads();

  int w = tid >> 6, lane = tid & 63, lr = lane & 15, lq = lane >> 4;
  bf16x8 a0 = *(const bf16x8*)&attB[(w * 16 + lr) * 72 + lq * 8];
  bf16x8 a1 = *(const bf16x8*)&attB[(w * 16 + lr) * 72 + 32 + lq * 8];
#pragma unroll
  for (int s = 0; s < 16; ++s) {
    int gc = cg * 256 + s * 16 + lr;
    const __hip_bfloat16* Bp = WhT + ((size_t)b * Hd + gc) * RP + lq * 8;
    f32x4 acc = {};
    acc = MFMA(a0, *(const bf16x8*)Bp, acc);
    acc = MFMA(a1, *(const bf16x8*)(Bp + 32), acc);
#pragma unroll
    for (int r = 0; r < 4; ++r) {
      float v = acc[r];
      v = v > 0.f ? v : expf(v) - 1.f;  // elu
      size_t off = ((size_t)b * RP + w * 16 + lq * 4 + r) * Hd + gc;
      if (LAYER == 2) {
        v += xres[off];
        hf[off] = v;
      }
      hb[off] = __float2bfloat16(v);
    }
  }
}

// Pool softmax + weighted sum + final linear for one dialogue.
__device__ void pool_task(char* smemraw, int b, const float* __restrict__ sraw,
                          const float* __restrict__ h2,
                          const __hip_bfloat16* __restrict__ Wlt,
                          const float* __restrict__ bl,
                          float* __restrict__ out) {
  float* sc = reinterpret_cast<float*>(smemraw);         // Nn floats
  float* ds = reinterpret_cast<float*>(smemraw + 256);   // Hd floats
  if (threadIdx.x < 64) {
    int j = threadIdx.x;
    float e = (j < Nn) ? sraw[b * RP + j] : -3.0e38f;
    float m = e;
#pragma unroll
    for (int off = 32; off; off >>= 1) m = fmaxf(m, __shfl_xor(m, off));
    float p = (j < Nn) ? expf(e - m) : 0.f;
    float s = p;
#pragma unroll
    for (int off = 32; off; off >>= 1) s += __shfl_xor(s, off);
    if (j < Nn) sc[j] = p / s;
  }
  __syncthreads();
  for (int h = threadIdx.x; h < Hd; h += 256) {
    float a = 0.f;
#pragma unroll 10
    for (int j = 0; j < Nn; ++j) a += sc[j] * h2[((size_t)b * RP + j) * Hd + h];
    ds[h] = a;
  }
  __syncthreads();
  for (int oo = 0; oo < 3; ++oo) {
    int o = oo * 256 + threadIdx.x;
    float acc = bl[o];
    const uint4* wr = (const uint4*)(Wlt + (size_t)o * Hd);
    for (int kk = 0; kk < Hd / 8; ++kk) {
      union { uint4 u; unsigned short s[8]; } w;
      w.u = wr[kk];
#pragma unroll
      for (int t = 0; t < 8; ++t)
        acc += ds[kk * 8 + t] * __uint_as_float((unsigned)w.s[t] << 16);
    }
    out[(size_t)b * On + o] = acc;
  }
}

// ===========================================================================
// Fused pipeline with full-grid barriers between stages. grid = 768 blocks,
// so every G-stage is exactly the proven standalone launch (768 blocks, one
// 64x64 tile each); A-stages use blocks [0,192)/[192,384) (distinct CUs);
// pool uses [384,448). Prep is folded in as stage 0 (same 6480 task bodies).
struct FusedArgs {
  // prep
  const float* wsrc[4];
  __hip_bfloat16* wdst[4];
  const float* emb;
  const int* ids;
  // tensors
  const __hip_bfloat16 *Wt1c, *Wt2c, *Wtac, *Wltc;  // same as wdst, const view
  __hip_bfloat16 *xb, *WhT1, *WhT2, *h1b, *h2b;
  float *xres, *h2f;
  const float *b1, *a1, *ab1, *b2, *a2, *ab2, *ba, *vv, *bl;
  const int* adj;
  float* aux;   // ssrc1,sdst1,ssrc2,sdst2,sraw (5*Bn*RP), zeroed in stage 0
  float* out;
  int* bar;     // 6 ints, zeroed by hipMemsetAsync
};

__global__ __launch_bounds__(256, 3) void fused_kernel(FusedArgs f) {
  __shared__ __align__(16) char smem[20992];
  int g = blockIdx.x;
  int tid = threadIdx.x;
  float* ssrc1 = f.aux;
  float* sdst1 = f.aux + Bn * RP;
  float* ssrc2 = f.aux + 2 * Bn * RP;
  float* sdst2 = f.aux + 3 * Bn * RP;
  float* sraw = f.aux + 4 * Bn * RP;

  // ---- stage 0: prep (transpose weights, gather+PE, zero accumulators) ----
  for (int t = g; t < 6480; t += NBLK) {
    if (t < 2304) {
      float* tile = reinterpret_cast<float*>(smem);  // [32][33]
      int job = t / 576, tt = t % 576;
      const float* W = f.wsrc[job];
      __hip_bfloat16* Wt = f.wdst[job];
      int tx = (tt % 24) * 32, ty = (tt / 24) * 32;
      int c = tid & 31, r0 = tid >> 5;
      for (int r = r0; r < 32; r += 8)
        tile[r * 33 + c] = W[(size_t)(tx + r) * Hd + ty + c];
      __syncthreads();
      for (int r = r0; r < 32; r += 8)
        Wt[(size_t)(ty + r) * Hd + tx + c] = __float2bfloat16(tile[c * 33 + r]);
      __syncthreads();  // protect tile before next task reuses it
    } else if (t < 6400) {
      int bn = t - 2304;  // b*RP + i
      int b = bn >> 6, i = bn & 63;
      __hip_bfloat16* xbo = f.xb + (size_t)bn * Hd;
      float* xro = f.xres + (size_t)bn * Hd;
      if (i < Nn) {
        int id = f.ids[b * Nn + i];
        const float* src = f.emb + ((size_t)b * Ln + id) * Hd;
        const float kLog = 9.210340371976184f / (float)Hd;  // ln(10000)/H
        for (int h = tid; h < Hd; h += 256) {
          float freq = expf(-(float)(h & ~1) * kLog);
          float ang = (float)i * freq;
          float v = src[h] + ((h & 1) ? cosf(ang) : sinf(ang));
          xbo[h] = __float2bfloat16(v);
          xro[h] = v;
        }
      } else {
        for (int h = tid; h < Hd; h += 256) {
          xbo[h] = __float2bfloat16(0.f);
          xro[h] = 0.f;
        }
      }
    } else {
      int idx = (t - 6400) * 256 + tid;
      if (idx < AUXW) f.aux[idx] = 0.f;
    }
  }
  grid_bar(f.bar + 0);

  // ---- G1: xb @ W1 (+ssrc1/sdst1 fused epilogue) ----
  gemm_task<0>(smem, g / 12, (g % 12) * 64, f.xb, f.Wt1c, f.b1, f.WhT1, f.a1,
               ssrc1, sdst1);
  grid_bar(f.bar + 1);

  // ---- A1: attention apply, layer 1 ----
  if (g < 192) {
    attf_task<1>(smem, g / 3, g % 3, ssrc1, sdst1, f.adj, f.ab1, f.WhT1,
                 nullptr, nullptr, f.h1b);
  }
  grid_bar(f.bar + 2);

  // ---- G2: h1 @ W2 ----
  gemm_task<0>(smem, g / 12, (g % 12) * 64, f.h1b, f.Wt2c, f.b2, f.WhT2, f.a2,
               ssrc2, sdst2);
  grid_bar(f.bar + 3);

  // ---- A2: attention apply, layer 2 (+residual) ----
  if (g >= 192 && g < 384) {
    int t = g - 192;
    attf_task<2>(smem, t / 3, t % 3, ssrc2, sdst2, f.adj, f.ab2, f.WhT2,
                 f.xres, f.h2f, f.h2b);
  }
  grid_bar(f.bar + 4);

  // ---- G3: pooling scores sraw = tanh(h2 @ Wa + ba) . v ----
  gemm_task<1>(smem, g / 12, (g % 12) * 64, f.h2b, f.Wtac, f.ba, nullptr, f.vv,
               sraw, nullptr);
  grid_bar(f.bar + 5);

  // ---- P: pool + final linear ----
  if (g >= 384 && g < 448) {
    pool_task(smem, g - 384, sraw, f.h2f, f.Wltc, f.bl, f.out);
  }
}

// ===========================================================================
extern "C" void kernel_launch(void* const* d_in, const int* in_sizes, int n_in,
                              void* d_out, int out_size, void* d_ws, size_t ws_size,
                              hipStream_t stream) {
  const float* emb = (const float*)d_in[0];
  const int* ids = (const int*)d_in[1];
  const int* adj = (const int*)d_in[2];
  const float* W1 = (const float*)d_in[3];
  const float* b1 = (const float*)d_in[4];
  const float* a1 = (const float*)d_in[5];
  const float* ab1 = (const float*)d_in[6];
  const float* W2 = (const float*)d_in[7];
  const float* b2 = (const float*)d_in[8];
  const float* a2 = (const float*)d_in[9];
  const float* ab2 = (const float*)d_in[10];
  const float* Wa = (const float*)d_in[11];
  const float* ba = (const float*)d_in[12];
  const float* vv = (const float*)d_in[13];
  const float* Wl = (const float*)d_in[14];
  const float* bl = (const float*)d_in[15];
  float* out = (float*)d_out;

  char* p = (char*)d_ws;
  auto alloc = [&](size_t bytes) {
    char* r = p;
    p += (bytes + 255) & ~(size_t)255;
    return r;
  };
  __hip_bfloat16* Wt1 = (__hip_bfloat16*)alloc((size_t)Hd * Hd * 2);
  __hip_bfloat16* Wt2 = (__hip_bfloat16*)alloc((size_t)Hd * Hd * 2);
  __hip_bfloat16* Wta = (__hip_bfloat16*)alloc((size_t)Hd * Hd * 2);
  __hip_bfloat16* Wlt = (__hip_bfloat16*)alloc((size_t)Hd * On * 2);
  float* aux = (float*)alloc((size_t)AUXW * 4);
  int* bar = (int*)alloc(64);
  __hip_bfloat16* xb = (__hip_bfloat16*)alloc((size_t)Bn * RP * Hd * 2);
  float* xres = (float*)alloc((size_t)Bn * RP * Hd * 4);
  __hip_bfloat16* WhT1 = (__hip_bfloat16*)alloc((size_t)Bn * Hd * RP * 2);
  __hip_bfloat16* WhT2 = (__hip_bfloat16*)alloc((size_t)Bn * Hd * RP * 2);
  __hip_bfloat16* h1b = (__hip_bfloat16*)alloc((size_t)Bn * RP * Hd * 2);
  __hip_bfloat16* h2b = (__hip_bfloat16*)alloc((size_t)Bn * RP * Hd * 2);
  float* h2f = (float*)alloc((size_t)Bn * RP * Hd * 4);

  // barrier counters must be zero before any block arrives (ws is poisoned
  // each iteration); stream-ordered, graph-capturable.
  hipMemsetAsync(bar, 0, 64, stream);

  FusedArgs fa;
  fa.wsrc[0] = W1; fa.wsrc[1] = W2; fa.wsrc[2] = Wa; fa.wsrc[3] = Wl;
  fa.wdst[0] = Wt1; fa.wdst[1] = Wt2; fa.wdst[2] = Wta; fa.wdst[3] = Wlt;
  fa.emb = emb; fa.ids = ids;
  fa.Wt1c = Wt1; fa.Wt2c = Wt2; fa.Wtac = Wta; fa.Wltc = Wlt;
  fa.xb = xb; fa.WhT1 = WhT1; fa.WhT2 = WhT2; fa.h1b = h1b; fa.h2b = h2b;
  fa.xres = xres; fa.h2f = h2f;
  fa.b1 = b1; fa.a1 = a1; fa.ab1 = ab1;
  fa.b2 = b2; fa.a2 = a2; fa.ab2 = ab2;
  fa.ba = ba; fa.vv = vv; fa.bl = bl;
  fa.adj = adj;
  fa.aux = aux; fa.out = out; fa.bar = bar;

  fused_kernel<<<NBLK, 256, 0, stream>>>(fa);
}

// Round 3
// 683.874 us; speedup vs baseline: 1.3744x; 1.3744x over previous
//
#include <hip/hip_runtime.h>
#include <hip/hip_bf16.h>
#include <math.h>

typedef __attribute__((ext_vector_type(8))) short bf16x8;
typedef __attribute__((ext_vector_type(4))) float f32x4;
typedef __attribute__((ext_vector_type(4))) unsigned short u16x4;

constexpr int Bn = 64;    // dialogues
constexpr int Ln = 512;   // utterances
constexpr int Hd = 768;   // hidden
constexpr int Nn = 50;    // nodes per dialogue
constexpr int On = 768;   // output dim
constexpr int RP = 64;    // padded rows per dialogue (M = Bn*RP = 4096)

constexpr int NBLK = 768;                 // 3 blocks/CU on 256 CUs, all resident
constexpr int AUXW = 5 * Bn * RP;         // zeroed accumulator words
constexpr int BARSTRIDE = 32;             // ints; 128B between barrier counters

__device__ __forceinline__ f32x4 MFMA(bf16x8 a, bf16x8 b, f32x4 c) {
  return __builtin_amdgcn_mfma_f32_16x16x32_bf16(a, b, c, 0, 0, 0);
}
__device__ __forceinline__ unsigned short f2bb(float v) {
  __hip_bfloat16 h = __float2bfloat16(v);
  return *(unsigned short*)&h;
}

// ===========================================================================
// Single-use full-grid barrier, fence-minimal.
// R2 lesson: agent-scope ACQUIRE per poll = full L1+L2 invalidate per
// iteration (gfx940+ memory model) -> fence storm, 808us kernel. Here:
//   - exactly ONE release fence (L2 writeback) per block, before arrival
//   - relaxed RMW spin (RMW executes at the coherence point -> hang-proof,
//     no cache maintenance) with s_sleep backoff to bound same-line pressure
//   - exactly ONE acquire fence (L1+L2 invalidate) per block, after exit
// All NBLK blocks are co-resident by construction (launch_bounds(256,3),
// VGPR 52, LDS 20.5KB -> 3/CU on 256 CUs), so arrive-and-poll cannot livelock.
__device__ __forceinline__ void grid_bar(int* bar) {
  __syncthreads();  // also drains each wave's stores to L2 (vmcnt(0))
  if (threadIdx.x == 0) {
    __builtin_amdgcn_fence(__ATOMIC_RELEASE, "agent");  // one wbL2, my XCD
    __hip_atomic_fetch_add(bar, 1, __ATOMIC_RELAXED, __HIP_MEMORY_SCOPE_AGENT);
    while (__hip_atomic_fetch_add(bar, 0, __ATOMIC_RELAXED,
                                  __HIP_MEMORY_SCOPE_AGENT) < NBLK) {
      __builtin_amdgcn_s_sleep(64);  // ~4096 cyc backoff
    }
    __builtin_amdgcn_fence(__ATOMIC_ACQUIRE, "agent");  // one inv, my XCD
  }
  __syncthreads();
}

// ===========================================================================
// Task bodies — verbatim from the proven standalone kernels (R6 lineage),
// __shared__ replaced by the caller's LDS arena. Every task body is
// entered/exited through a __syncthreads() (inside grid_bar), so arena reuse
// across stages is race-free.

// Per-dialogue GEMM tile: C = A[b*64..+64, :] @ Wt^T + bias, 64x64 cols.
// EPI 0: write Wh^T + fused src/dst dots. EPI 1: tanh(C+bias).v into o1.
template <int EPI>
__device__ void gemm_task(char* smemraw, int b, int col0,
                          const __hip_bfloat16* __restrict__ A,
                          const __hip_bfloat16* __restrict__ Bt,
                          const float* __restrict__ bias,
                          __hip_bfloat16* __restrict__ WhT,
                          const float* __restrict__ avec,
                          float* __restrict__ o1, float* __restrict__ o2) {
  typedef __hip_bfloat16 Tile[64][40];
  Tile* As = reinterpret_cast<Tile*>(smemraw);            // [2][64][40]
  Tile* Bs = reinterpret_cast<Tile*>(smemraw + 10240);    // [2][64][40]
  int tid = threadIdx.x;
  int wave = tid >> 6, lane = tid & 63;
  int lr = lane & 15, lq = lane >> 4;
  int row0 = b * RP;
  int sr = tid >> 2, sk = (tid & 3) * 8;
  const __hip_bfloat16* Ap = A + (size_t)(row0 + sr) * Hd + sk;
  const __hip_bfloat16* Bp = Bt + (size_t)(col0 + sr) * Hd + sk;
  uint4 ra = *(const uint4*)Ap;
  uint4 rb = *(const uint4*)Bp;
  *(uint4*)&As[0][sr][sk] = ra;
  *(uint4*)&Bs[0][sr][sk] = rb;
  f32x4 acc[4] = {};
  __syncthreads();
  int cur = 0;
  for (int kt = 32; kt < Hd; kt += 32) {
    ra = *(const uint4*)(Ap + kt);
    rb = *(const uint4*)(Bp + kt);
    bf16x8 af = *(const bf16x8*)&As[cur][wave * 16 + lr][lq * 8];
#pragma unroll
    for (int ct = 0; ct < 4; ++ct)
      acc[ct] = MFMA(af, *(const bf16x8*)&Bs[cur][ct * 16 + lr][lq * 8], acc[ct]);
    *(uint4*)&As[cur ^ 1][sr][sk] = ra;
    *(uint4*)&Bs[cur ^ 1][sr][sk] = rb;
    __syncthreads();
    cur ^= 1;
  }
  {
    bf16x8 af = *(const bf16x8*)&As[cur][wave * 16 + lr][lq * 8];
#pragma unroll
    for (int ct = 0; ct < 4; ++ct)
      acc[ct] = MFMA(af, *(const bf16x8*)&Bs[cur][ct * 16 + lr][lq * 8], acc[ct]);
  }
  int lrow0 = wave * 16 + lq * 4;  // local row base (0..60, mult of 4)
  if (EPI == 0) {
    float ps[4] = {}, pd[4] = {};
#pragma unroll
    for (int ct = 0; ct < 4; ++ct) {
      int gc = col0 + ct * 16 + lr;
      float bv = bias[gc];
      float a_s = avec[gc], a_d = avec[Hd + gc];
      u16x4 pk;
#pragma unroll
      for (int r = 0; r < 4; ++r) {
        float v = acc[ct][r] + bv;
        pk[r] = f2bb(v);
        ps[r] += v * a_s;
        pd[r] += v * a_d;
      }
      *(u16x4*)(WhT + ((size_t)b * Hd + gc) * RP + lrow0) = pk;
    }
#pragma unroll
    for (int off = 8; off; off >>= 1)
#pragma unroll
      for (int r = 0; r < 4; ++r) {
        ps[r] += __shfl_xor(ps[r], off);
        pd[r] += __shfl_xor(pd[r], off);
      }
    if (lr == 0)
#pragma unroll
      for (int r = 0; r < 4; ++r) {
        int row = lrow0 + r;
        if (row < Nn) {
          atomicAdd(&o1[b * RP + row], ps[r]);
          atomicAdd(&o2[b * RP + row], pd[r]);
        }
      }
  } else {
    float pr[4] = {};
#pragma unroll
    for (int ct = 0; ct < 4; ++ct) {
      int gc = col0 + ct * 16 + lr;
      float bv = bias[gc];
      float vv_ = avec[gc];
#pragma unroll
      for (int r = 0; r < 4; ++r) pr[r] += tanhf(acc[ct][r] + bv) * vv_;
    }
#pragma unroll
    for (int off = 8; off; off >>= 1)
#pragma unroll
      for (int r = 0; r < 4; ++r) pr[r] += __shfl_xor(pr[r], off);
    if (lr == 0)
#pragma unroll
      for (int r = 0; r < 4; ++r) {
        int row = lrow0 + r;
        if (row < Nn) atomicAdd(&o1[b * RP + row], pr[r]);
      }
  }
}

// MFMA attention apply for one (dialogue b, col-group cg of 256 cols).
template <int LAYER>
__device__ void attf_task(char* smemraw, int b, int cg,
                          const float* __restrict__ ssrc,
                          const float* __restrict__ sdst,
                          const int* __restrict__ adj,
                          const float* __restrict__ ab,
                          const __hip_bfloat16* __restrict__ WhT,
                          const float* __restrict__ xres,
                          float* __restrict__ hf,
                          __hip_bfloat16* __restrict__ hb) {
  float* attL = reinterpret_cast<float*>(smemraw);                     // Nn*52
  __hip_bfloat16* attB =
      reinterpret_cast<__hip_bfloat16*>(smemraw + Nn * 52 * 4);        // 64*72
  int tid = threadIdx.x;
  float abv = ab[0];
  for (int i = tid; i < 64 * 72; i += 256) attB[i] = __float2bfloat16(0.f);
  for (int idx = tid; idx < Nn * Nn; idx += 256) {
    int i = idx / Nn, j = idx - i * Nn;
    float t = ssrc[b * RP + i] + sdst[b * RP + j] + abv;
    t = t > 0.f ? t : 0.3f * t;  // leaky_relu 0.3
    attL[i * 52 + j] = (adj[(size_t)b * Nn * Nn + idx] > 0) ? t : -9.0e15f;
  }
  __syncthreads();
  if (tid < Nn) {
    float m = -3.0e38f;
    for (int j = 0; j < Nn; ++j) m = fmaxf(m, attL[tid * 52 + j]);
    float s = 0.f;
    for (int j = 0; j < Nn; ++j) {
      float p = expf(attL[tid * 52 + j] - m);
      attL[tid * 52 + j] = p;
      s += p;
    }
    float inv = 1.f / s;
    for (int j = 0; j < Nn; ++j) attL[tid * 52 + j] *= inv;
  }
  __syncthreads();
  for (int idx = tid; idx < Nn * Nn; idx += 256) {
    int i = idx / Nn, j = idx - i * Nn;
    attB[i * 72 + j] = __float2bfloat16(attL[i * 52 + j]);
  }
  __syncthreads();

  int w = tid >> 6, lane = tid & 63, lr = lane & 15, lq = lane >> 4;
  bf16x8 a0 = *(const bf16x8*)&attB[(w * 16 + lr) * 72 + lq * 8];
  bf16x8 a1 = *(const bf16x8*)&attB[(w * 16 + lr) * 72 + 32 + lq * 8];
#pragma unroll
  for (int s = 0; s < 16; ++s) {
    int gc = cg * 256 + s * 16 + lr;
    const __hip_bfloat16* Bp = WhT + ((size_t)b * Hd + gc) * RP + lq * 8;
    f32x4 acc = {};
    acc = MFMA(a0, *(const bf16x8*)Bp, acc);
    acc = MFMA(a1, *(const bf16x8*)(Bp + 32), acc);
#pragma unroll
    for (int r = 0; r < 4; ++r) {
      float v = acc[r];
      v = v > 0.f ? v : expf(v) - 1.f;  // elu
      size_t off = ((size_t)b * RP + w * 16 + lq * 4 + r) * Hd + gc;
      if (LAYER == 2) {
        v += xres[off];
        hf[off] = v;
      }
      hb[off] = __float2bfloat16(v);
    }
  }
}

// Pool softmax + weighted sum + final linear for one dialogue.
__device__ void pool_task(char* smemraw, int b, const float* __restrict__ sraw,
                          const float* __restrict__ h2,
                          const __hip_bfloat16* __restrict__ Wlt,
                          const float* __restrict__ bl,
                          float* __restrict__ out) {
  float* sc = reinterpret_cast<float*>(smemraw);         // Nn floats
  float* ds = reinterpret_cast<float*>(smemraw + 256);   // Hd floats
  if (threadIdx.x < 64) {
    int j = threadIdx.x;
    float e = (j < Nn) ? sraw[b * RP + j] : -3.0e38f;
    float m = e;
#pragma unroll
    for (int off = 32; off; off >>= 1) m = fmaxf(m, __shfl_xor(m, off));
    float p = (j < Nn) ? expf(e - m) : 0.f;
    float s = p;
#pragma unroll
    for (int off = 32; off; off >>= 1) s += __shfl_xor(s, off);
    if (j < Nn) sc[j] = p / s;
  }
  __syncthreads();
  for (int h = threadIdx.x; h < Hd; h += 256) {
    float a = 0.f;
#pragma unroll 10
    for (int j = 0; j < Nn; ++j) a += sc[j] * h2[((size_t)b * RP + j) * Hd + h];
    ds[h] = a;
  }
  __syncthreads();
  for (int oo = 0; oo < 3; ++oo) {
    int o = oo * 256 + threadIdx.x;
    float acc = bl[o];
    const uint4* wr = (const uint4*)(Wlt + (size_t)o * Hd);
    for (int kk = 0; kk < Hd / 8; ++kk) {
      union { uint4 u; unsigned short s[8]; } w;
      w.u = wr[kk];
#pragma unroll
      for (int t = 0; t < 8; ++t)
        acc += ds[kk * 8 + t] * __uint_as_float((unsigned)w.s[t] << 16);
    }
    out[(size_t)b * On + o] = acc;
  }
}

// ===========================================================================
// Fused pipeline with full-grid barriers between stages. grid = 768 blocks,
// so every G-stage is exactly the proven standalone launch (768 blocks, one
// 64x64 tile each); A-stages use blocks [0,192)/[192,384); pool [384,448).
struct FusedArgs {
  // prep
  const float* wsrc[4];
  __hip_bfloat16* wdst[4];
  const float* emb;
  const int* ids;
  // tensors
  const __hip_bfloat16 *Wt1c, *Wt2c, *Wtac, *Wltc;  // same as wdst, const view
  __hip_bfloat16 *xb, *WhT1, *WhT2, *h1b, *h2b;
  float *xres, *h2f;
  const float *b1, *a1, *ab1, *b2, *a2, *ab2, *ba, *vv, *bl;
  const int* adj;
  float* aux;   // ssrc1,sdst1,ssrc2,sdst2,sraw (5*Bn*RP), zeroed in stage 0
  float* out;
  int* bar;     // 6 counters, 128B apart, zeroed by hipMemsetAsync
};

__global__ __launch_bounds__(256, 3) void fused_kernel(FusedArgs f) {
  __shared__ __align__(16) char smem[20992];
  int g = blockIdx.x;
  int tid = threadIdx.x;
  float* ssrc1 = f.aux;
  float* sdst1 = f.aux + Bn * RP;
  float* ssrc2 = f.aux + 2 * Bn * RP;
  float* sdst2 = f.aux + 3 * Bn * RP;
  float* sraw = f.aux + 4 * Bn * RP;

  // ---- stage 0: prep (transpose weights, gather+PE, zero accumulators) ----
  for (int t = g; t < 6480; t += NBLK) {
    if (t < 2304) {
      float* tile = reinterpret_cast<float*>(smem);  // [32][33]
      int job = t / 576, tt = t % 576;
      const float* W = f.wsrc[job];
      __hip_bfloat16* Wt = f.wdst[job];
      int tx = (tt % 24) * 32, ty = (tt / 24) * 32;
      int c = tid & 31, r0 = tid >> 5;
      for (int r = r0; r < 32; r += 8)
        tile[r * 33 + c] = W[(size_t)(tx + r) * Hd + ty + c];
      __syncthreads();
      for (int r = r0; r < 32; r += 8)
        Wt[(size_t)(ty + r) * Hd + tx + c] = __float2bfloat16(tile[c * 33 + r]);
      __syncthreads();  // protect tile before next task reuses it
    } else if (t < 6400) {
      int bn = t - 2304;  // b*RP + i
      int b = bn >> 6, i = bn & 63;
      __hip_bfloat16* xbo = f.xb + (size_t)bn * Hd;
      float* xro = f.xres + (size_t)bn * Hd;
      if (i < Nn) {
        int id = f.ids[b * Nn + i];
        const float* src = f.emb + ((size_t)b * Ln + id) * Hd;
        const float kLog = 9.210340371976184f / (float)Hd;  // ln(10000)/H
        for (int h = tid; h < Hd; h += 256) {
          float freq = expf(-(float)(h & ~1) * kLog);
          float ang = (float)i * freq;
          float v = src[h] + ((h & 1) ? cosf(ang) : sinf(ang));
          xbo[h] = __float2bfloat16(v);
          xro[h] = v;
        }
      } else {
        for (int h = tid; h < Hd; h += 256) {
          xbo[h] = __float2bfloat16(0.f);
          xro[h] = 0.f;
        }
      }
    } else {
      int idx = (t - 6400) * 256 + tid;
      if (idx < AUXW) f.aux[idx] = 0.f;
    }
  }
  grid_bar(f.bar + 0 * BARSTRIDE);

  // ---- G1: xb @ W1 (+ssrc1/sdst1 fused epilogue) ----
  gemm_task<0>(smem, g / 12, (g % 12) * 64, f.xb, f.Wt1c, f.b1, f.WhT1, f.a1,
               ssrc1, sdst1);
  grid_bar(f.bar + 1 * BARSTRIDE);

  // ---- A1: attention apply, layer 1 ----
  if (g < 192) {
    attf_task<1>(smem, g / 3, g % 3, ssrc1, sdst1, f.adj, f.ab1, f.WhT1,
                 nullptr, nullptr, f.h1b);
  }
  grid_bar(f.bar + 2 * BARSTRIDE);

  // ---- G2: h1 @ W2 ----
  gemm_task<0>(smem, g / 12, (g % 12) * 64, f.h1b, f.Wt2c, f.b2, f.WhT2, f.a2,
               ssrc2, sdst2);
  grid_bar(f.bar + 3 * BARSTRIDE);

  // ---- A2: attention apply, layer 2 (+residual) ----
  if (g >= 192 && g < 384) {
    int t = g - 192;
    attf_task<2>(smem, t / 3, t % 3, ssrc2, sdst2, f.adj, f.ab2, f.WhT2,
                 f.xres, f.h2f, f.h2b);
  }
  grid_bar(f.bar + 4 * BARSTRIDE);

  // ---- G3: pooling scores sraw = tanh(h2 @ Wa + ba) . v ----
  gemm_task<1>(smem, g / 12, (g % 12) * 64, f.h2b, f.Wtac, f.ba, nullptr, f.vv,
               sraw, nullptr);
  grid_bar(f.bar + 5 * BARSTRIDE);

  // ---- P: pool + final linear ----
  if (g >= 384 && g < 448) {
    pool_task(smem, g - 384, sraw, f.h2f, f.Wltc, f.bl, f.out);
  }
}

// ===========================================================================
extern "C" void kernel_launch(void* const* d_in, const int* in_sizes, int n_in,
                              void* d_out, int out_size, void* d_ws, size_t ws_size,
                              hipStream_t stream) {
  const float* emb = (const float*)d_in[0];
  const int* ids = (const int*)d_in[1];
  const int* adj = (const int*)d_in[2];
  const float* W1 = (const float*)d_in[3];
  const float* b1 = (const float*)d_in[4];
  const float* a1 = (const float*)d_in[5];
  const float* ab1 = (const float*)d_in[6];
  const float* W2 = (const float*)d_in[7];
  const float* b2 = (const float*)d_in[8];
  const float* a2 = (const float*)d_in[9];
  const float* ab2 = (const float*)d_in[10];
  const float* Wa = (const float*)d_in[11];
  const float* ba = (const float*)d_in[12];
  const float* vv = (const float*)d_in[13];
  const float* Wl = (const float*)d_in[14];
  const float* bl = (const float*)d_in[15];
  float* out = (float*)d_out;

  char* p = (char*)d_ws;
  auto alloc = [&](size_t bytes) {
    char* r = p;
    p += (bytes + 255) & ~(size_t)255;
    return r;
  };
  __hip_bfloat16* Wt1 = (__hip_bfloat16*)alloc((size_t)Hd * Hd * 2);
  __hip_bfloat16* Wt2 = (__hip_bfloat16*)alloc((size_t)Hd * Hd * 2);
  __hip_bfloat16* Wta = (__hip_bfloat16*)alloc((size_t)Hd * Hd * 2);
  __hip_bfloat16* Wlt = (__hip_bfloat16*)alloc((size_t)Hd * On * 2);
  float* aux = (float*)alloc((size_t)AUXW * 4);
  int* bar = (int*)alloc(6 * BARSTRIDE * 4);
  __hip_bfloat16* xb = (__hip_bfloat16*)alloc((size_t)Bn * RP * Hd * 2);
  float* xres = (float*)alloc((size_t)Bn * RP * Hd * 4);
  __hip_bfloat16* WhT1 = (__hip_bfloat16*)alloc((size_t)Bn * Hd * RP * 2);
  __hip_bfloat16* WhT2 = (__hip_bfloat16*)alloc((size_t)Bn * Hd * RP * 2);
  __hip_bfloat16* h1b = (__hip_bfloat16*)alloc((size_t)Bn * RP * Hd * 2);
  __hip_bfloat16* h2b = (__hip_bfloat16*)alloc((size_t)Bn * RP * Hd * 2);
  float* h2f = (float*)alloc((size_t)Bn * RP * Hd * 4);

  // barrier counters must be zero before any block arrives (ws is poisoned
  // each iteration); stream-ordered, graph-capturable.
  hipMemsetAsync(bar, 0, 6 * BARSTRIDE * 4, stream);

  FusedArgs fa;
  fa.wsrc[0] = W1; fa.wsrc[1] = W2; fa.wsrc[2] = Wa; fa.wsrc[3] = Wl;
  fa.wdst[0] = Wt1; fa.wdst[1] = Wt2; fa.wdst[2] = Wta; fa.wdst[3] = Wlt;
  fa.emb = emb; fa.ids = ids;
  fa.Wt1c = Wt1; fa.Wt2c = Wt2; fa.Wtac = Wta; fa.Wltc = Wlt;
  fa.xb = xb; fa.WhT1 = WhT1; fa.WhT2 = WhT2; fa.h1b = h1b; fa.h2b = h2b;
  fa.xres = xres; fa.h2f = h2f;
  fa.b1 = b1; fa.a1 = a1; fa.ab1 = ab1;
  fa.b2 = b2; fa.a2 = a2; fa.ab2 = ab2;
  fa.ba = ba; fa.vv = vv; fa.bl = bl;
  fa.adj = adj;
  fa.aux = aux; fa.out = out; fa.bar = bar;

  fused_kernel<<<NBLK, 256, 0, stream>>>(fa);
}

// Round 4
// 265.837 us; speedup vs baseline: 3.5357x; 2.5725x over previous
//
#include <hip/hip_runtime.h>
#include <hip/hip_bf16.h>
#include <math.h>

typedef __attribute__((ext_vector_type(8))) short bf16x8;
typedef __attribute__((ext_vector_type(4))) float f32x4;
typedef __attribute__((ext_vector_type(4))) unsigned short u16x4;

constexpr int Bn = 64;    // dialogues
constexpr int Ln = 512;   // utterances
constexpr int Hd = 768;   // hidden
constexpr int Nn = 50;    // nodes per dialogue
constexpr int On = 768;   // output dim
constexpr int RP = 64;    // padded rows per dialogue (M = Bn*RP = 4096)

__device__ __forceinline__ f32x4 MFMA(bf16x8 a, bf16x8 b, f32x4 c) {
  return __builtin_amdgcn_mfma_f32_16x16x32_bf16(a, b, c, 0, 0, 0);
}
__device__ __forceinline__ unsigned short f2bb(float v) {
  __hip_bfloat16 h = __float2bfloat16(v);
  return *(unsigned short*)&h;
}

// ===========================================================================
// prep, one launch, job ranges by blockIdx.x:
//   [0,2304)      transpose+cvt W1,W2,Wa,Wl (f32 -> bf16^T)
//   [2304,6400)   gather+PE into padded xb (bf16) / xres (f32); pad rows = 0
//   [6400,6480)   zero the 5*Bn*RP aux accumulator region
struct PrepArgs {
  const float* src[4];
  __hip_bfloat16* dst[4];
  const float* emb;
  const int* ids;
  float* xres;
  __hip_bfloat16* xb;
  float* aux;
};

__global__ __launch_bounds__(256) void prep_kernel(PrepArgs a) {
  int bx = blockIdx.x;
  if (bx < 2304) {
    __shared__ float tile[32][33];
    int job = bx / 576, t = bx % 576;
    const float* W = a.src[job];
    __hip_bfloat16* Wt = a.dst[job];
    int tx = (t % 24) * 32, ty = (t / 24) * 32;
    int c = threadIdx.x & 31, r0 = threadIdx.x >> 5;
    for (int r = r0; r < 32; r += 8)
      tile[r][c] = W[(size_t)(tx + r) * Hd + ty + c];
    __syncthreads();
    for (int r = r0; r < 32; r += 8)
      Wt[(size_t)(ty + r) * Hd + tx + c] = __float2bfloat16(tile[c][r]);
  } else if (bx < 6400) {
    int bn = bx - 2304;          // b*RP + i
    int b = bn >> 6, i = bn & 63;
    __hip_bfloat16* xbo = a.xb + (size_t)bn * Hd;
    float* xro = a.xres + (size_t)bn * Hd;
    if (i < Nn) {
      int id = a.ids[b * Nn + i];
      const float* src = a.emb + ((size_t)b * Ln + id) * Hd;
      const float kLog = 9.210340371976184f / (float)Hd;  // ln(10000)/H
      for (int h = threadIdx.x; h < Hd; h += 256) {
        float freq = expf(-(float)(h & ~1) * kLog);
        float ang = (float)i * freq;
        float v = src[h] + ((h & 1) ? cosf(ang) : sinf(ang));
        xbo[h] = __float2bfloat16(v);
        xro[h] = v;
      }
    } else {
      for (int h = threadIdx.x; h < Hd; h += 256) {
        xbo[h] = __float2bfloat16(0.f);
        xro[h] = 0.f;
      }
    }
  } else {
    int idx = (bx - 6400) * 256 + threadIdx.x;
    if (idx < 5 * Bn * RP) a.aux[idx] = 0.f;
  }
}

// ===========================================================================
// Per-dialogue GEMM tile: C = A[b*64..+64, :] @ Wt^T + bias, 64x64 per block.
// grid = (Bn, 12). Double-buffered LDS K-loop, BK=64 (12 iters, half the
// barriers of the proven BK=32 version; accumulation order per acc[ct] is
// k, k+32, ... -> bit-identical numerics).
// EPI 0: write Wh^T (bf16, per-dialogue [Hd][RP], packed u16x4) + fused
//        src/dst dots into o1/o2 (guarded to local row < Nn).
// EPI 1: no write; atomicAdd(o1[b*RP+row], tanh(C+bias) . avec).
template <int EPI>
__global__ __launch_bounds__(256) void gemm_kernel(
    const __hip_bfloat16* __restrict__ A, const __hip_bfloat16* __restrict__ Bt,
    const float* __restrict__ bias, __hip_bfloat16* __restrict__ WhT,
    const float* __restrict__ avec, float* __restrict__ o1,
    float* __restrict__ o2) {
  __shared__ __hip_bfloat16 As[2][64][72];   // 64 rows x 64 cols + 8 pad
  __shared__ __hip_bfloat16 Bs[2][64][72];
  int tid = threadIdx.x;
  int wave = tid >> 6, lane = tid & 63;
  int lr = lane & 15, lq = lane >> 4;
  int b = blockIdx.x, col0 = blockIdx.y * 64;
  int row0 = b * RP;
  int sr = tid >> 2, sk = (tid & 3) * 8;
  const __hip_bfloat16* Ap = A + (size_t)(row0 + sr) * Hd + sk;
  const __hip_bfloat16* Bp = Bt + (size_t)(col0 + sr) * Hd + sk;
  uint4 ra0 = *(const uint4*)Ap;
  uint4 ra1 = *(const uint4*)(Ap + 32);
  uint4 rb0 = *(const uint4*)Bp;
  uint4 rb1 = *(const uint4*)(Bp + 32);
  *(uint4*)&As[0][sr][sk] = ra0;
  *(uint4*)&As[0][sr][sk + 32] = ra1;
  *(uint4*)&Bs[0][sr][sk] = rb0;
  *(uint4*)&Bs[0][sr][sk + 32] = rb1;
  f32x4 acc[4] = {};
  __syncthreads();
  int cur = 0;
  for (int kt = 64; kt < Hd; kt += 64) {
    ra0 = *(const uint4*)(Ap + kt);
    ra1 = *(const uint4*)(Ap + kt + 32);
    rb0 = *(const uint4*)(Bp + kt);
    rb1 = *(const uint4*)(Bp + kt + 32);
    bf16x8 af0 = *(const bf16x8*)&As[cur][wave * 16 + lr][lq * 8];
    bf16x8 af1 = *(const bf16x8*)&As[cur][wave * 16 + lr][32 + lq * 8];
#pragma unroll
    for (int ct = 0; ct < 4; ++ct) {
      acc[ct] = MFMA(af0, *(const bf16x8*)&Bs[cur][ct * 16 + lr][lq * 8], acc[ct]);
      acc[ct] = MFMA(af1, *(const bf16x8*)&Bs[cur][ct * 16 + lr][32 + lq * 8], acc[ct]);
    }
    *(uint4*)&As[cur ^ 1][sr][sk] = ra0;
    *(uint4*)&As[cur ^ 1][sr][sk + 32] = ra1;
    *(uint4*)&Bs[cur ^ 1][sr][sk] = rb0;
    *(uint4*)&Bs[cur ^ 1][sr][sk + 32] = rb1;
    __syncthreads();
    cur ^= 1;
  }
  {
    bf16x8 af0 = *(const bf16x8*)&As[cur][wave * 16 + lr][lq * 8];
    bf16x8 af1 = *(const bf16x8*)&As[cur][wave * 16 + lr][32 + lq * 8];
#pragma unroll
    for (int ct = 0; ct < 4; ++ct) {
      acc[ct] = MFMA(af0, *(const bf16x8*)&Bs[cur][ct * 16 + lr][lq * 8], acc[ct]);
      acc[ct] = MFMA(af1, *(const bf16x8*)&Bs[cur][ct * 16 + lr][32 + lq * 8], acc[ct]);
    }
  }
  int lrow0 = wave * 16 + lq * 4;  // local row base (0..60, mult of 4)
  if (EPI == 0) {
    float ps[4] = {}, pd[4] = {};
#pragma unroll
    for (int ct = 0; ct < 4; ++ct) {
      int gc = col0 + ct * 16 + lr;
      float bv = bias[gc];
      float a_s = avec[gc], a_d = avec[Hd + gc];
      u16x4 pk;
#pragma unroll
      for (int r = 0; r < 4; ++r) {
        float v = acc[ct][r] + bv;
        pk[r] = f2bb(v);
        ps[r] += v * a_s;
        pd[r] += v * a_d;
      }
      *(u16x4*)(WhT + ((size_t)b * Hd + gc) * RP + lrow0) = pk;
    }
#pragma unroll
    for (int off = 8; off; off >>= 1)
#pragma unroll
      for (int r = 0; r < 4; ++r) {
        ps[r] += __shfl_xor(ps[r], off);
        pd[r] += __shfl_xor(pd[r], off);
      }
    if (lr == 0)
#pragma unroll
      for (int r = 0; r < 4; ++r) {
        int row = lrow0 + r;
        if (row < Nn) {
          atomicAdd(&o1[b * RP + row], ps[r]);
          atomicAdd(&o2[b * RP + row], pd[r]);
        }
      }
  } else {
    float pr[4] = {};
#pragma unroll
    for (int ct = 0; ct < 4; ++ct) {
      int gc = col0 + ct * 16 + lr;
      float bv = bias[gc];
      float vv_ = avec[gc];
#pragma unroll
      for (int r = 0; r < 4; ++r) pr[r] += tanhf(acc[ct][r] + bv) * vv_;
    }
#pragma unroll
    for (int off = 8; off; off >>= 1)
#pragma unroll
      for (int r = 0; r < 4; ++r) pr[r] += __shfl_xor(pr[r], off);
    if (lr == 0)
#pragma unroll
      for (int r = 0; r < 4; ++r) {
        int row = lrow0 + r;
        if (row < Nn) atomicAdd(&o1[b * RP + row], pr[r]);
      }
  }
}

// ===========================================================================
// MFMA attention apply: grid = (Bn*12), block 256 (4 waves), 64 cols/block.
// (Was Bn*3 x 256 cols: widened 4x for latency hiding; softmax recomputed
// per block — bit-identical numerics, ~1us redundant cost.)
// att = softmax(mask(adj, leaky_relu(ssrc_i+sdst_j+ab))) built in LDS (f32),
// converted to zero-padded bf16 A-operand; B = WhT (global).
// h[row, gc] = elu(sum_j att[row][j] WhT[gc][j]) (+xres, +hf for LAYER 2).
template <int LAYER>
__global__ __launch_bounds__(256) void attf_kernel(
    const float* __restrict__ ssrc, const float* __restrict__ sdst,
    const int* __restrict__ adj, const float* __restrict__ ab,
    const __hip_bfloat16* __restrict__ WhT, const float* __restrict__ xres,
    float* __restrict__ hf, __hip_bfloat16* __restrict__ hb) {
  int b = blockIdx.x / 12, cg = blockIdx.x % 12;
  __shared__ float attL[Nn * 52];
  __shared__ __hip_bfloat16 attB[64 * 72];
  int tid = threadIdx.x;
  float abv = ab[0];
  for (int i = tid; i < 64 * 72; i += 256) attB[i] = __float2bfloat16(0.f);
  for (int idx = tid; idx < Nn * Nn; idx += 256) {
    int i = idx / Nn, j = idx - i * Nn;
    float t = ssrc[b * RP + i] + sdst[b * RP + j] + abv;
    t = t > 0.f ? t : 0.3f * t;  // leaky_relu 0.3
    attL[i * 52 + j] = (adj[(size_t)b * Nn * Nn + idx] > 0) ? t : -9.0e15f;
  }
  __syncthreads();
  if (tid < Nn) {
    float m = -3.0e38f;
    for (int j = 0; j < Nn; ++j) m = fmaxf(m, attL[tid * 52 + j]);
    float s = 0.f;
    for (int j = 0; j < Nn; ++j) {
      float p = expf(attL[tid * 52 + j] - m);
      attL[tid * 52 + j] = p;
      s += p;
    }
    float inv = 1.f / s;
    for (int j = 0; j < Nn; ++j) attL[tid * 52 + j] *= inv;
  }
  __syncthreads();
  for (int idx = tid; idx < Nn * Nn; idx += 256) {
    int i = idx / Nn, j = idx - i * Nn;
    attB[i * 72 + j] = __float2bfloat16(attL[i * 52 + j]);
  }
  __syncthreads();

  int w = tid >> 6, lane = tid & 63, lr = lane & 15, lq = lane >> 4;
  bf16x8 a0 = *(const bf16x8*)&attB[(w * 16 + lr) * 72 + lq * 8];
  bf16x8 a1 = *(const bf16x8*)&attB[(w * 16 + lr) * 72 + 32 + lq * 8];
#pragma unroll
  for (int s = 0; s < 4; ++s) {
    int gc = cg * 64 + s * 16 + lr;
    const __hip_bfloat16* Bp = WhT + ((size_t)b * Hd + gc) * RP + lq * 8;
    f32x4 acc = {};
    acc = MFMA(a0, *(const bf16x8*)Bp, acc);
    acc = MFMA(a1, *(const bf16x8*)(Bp + 32), acc);
#pragma unroll
    for (int r = 0; r < 4; ++r) {
      float v = acc[r];
      v = v > 0.f ? v : expf(v) - 1.f;  // elu
      size_t off = ((size_t)b * RP + w * 16 + lq * 4 + r) * Hd + gc;
      if (LAYER == 2) {
        v += xres[off];
        hf[off] = v;
      }
      hb[off] = __float2bfloat16(v);
    }
  }
}

// ===========================================================================
// Pool softmax + weighted sum + final linear. grid = Bn*3: 3 blocks per
// dialogue, each computing softmax+ds redundantly (bit-identical) and one
// 256-out slice of the final linear (3x latency hiding vs 1 block/dialogue).
__global__ __launch_bounds__(256) void poolfinal_kernel(
    const float* __restrict__ sraw, const float* __restrict__ h2,
    const __hip_bfloat16* __restrict__ Wlt, const float* __restrict__ bl,
    float* __restrict__ out) {
  int b = blockIdx.x / 3, q = blockIdx.x % 3;
  __shared__ float sc[Nn];
  __shared__ float ds[Hd];
  if (threadIdx.x < 64) {
    int j = threadIdx.x;
    float e = (j < Nn) ? sraw[b * RP + j] : -3.0e38f;
    float m = e;
#pragma unroll
    for (int off = 32; off; off >>= 1) m = fmaxf(m, __shfl_xor(m, off));
    float p = (j < Nn) ? expf(e - m) : 0.f;
    float s = p;
#pragma unroll
    for (int off = 32; off; off >>= 1) s += __shfl_xor(s, off);
    if (j < Nn) sc[j] = p / s;
  }
  __syncthreads();
  for (int h = threadIdx.x; h < Hd; h += 256) {
    float a = 0.f;
#pragma unroll 10
    for (int j = 0; j < Nn; ++j) a += sc[j] * h2[((size_t)b * RP + j) * Hd + h];
    ds[h] = a;
  }
  __syncthreads();
  {
    int o = q * 256 + threadIdx.x;
    float acc = bl[o];
    const uint4* wr = (const uint4*)(Wlt + (size_t)o * Hd);
    for (int kk = 0; kk < Hd / 8; ++kk) {
      union { uint4 u; unsigned short s[8]; } w;
      w.u = wr[kk];
#pragma unroll
      for (int t = 0; t < 8; ++t)
        acc += ds[kk * 8 + t] * __uint_as_float((unsigned)w.s[t] << 16);
    }
    out[(size_t)b * On + o] = acc;
  }
}

// ===========================================================================
extern "C" void kernel_launch(void* const* d_in, const int* in_sizes, int n_in,
                              void* d_out, int out_size, void* d_ws, size_t ws_size,
                              hipStream_t stream) {
  const float* emb = (const float*)d_in[0];
  const int* ids = (const int*)d_in[1];
  const int* adj = (const int*)d_in[2];
  const float* W1 = (const float*)d_in[3];
  const float* b1 = (const float*)d_in[4];
  const float* a1 = (const float*)d_in[5];
  const float* ab1 = (const float*)d_in[6];
  const float* W2 = (const float*)d_in[7];
  const float* b2 = (const float*)d_in[8];
  const float* a2 = (const float*)d_in[9];
  const float* ab2 = (const float*)d_in[10];
  const float* Wa = (const float*)d_in[11];
  const float* ba = (const float*)d_in[12];
  const float* vv = (const float*)d_in[13];
  const float* Wl = (const float*)d_in[14];
  const float* bl = (const float*)d_in[15];
  float* out = (float*)d_out;

  char* p = (char*)d_ws;
  auto alloc = [&](size_t bytes) {
    char* r = p;
    p += (bytes + 255) & ~(size_t)255;
    return r;
  };
  __hip_bfloat16* Wt1 = (__hip_bfloat16*)alloc((size_t)Hd * Hd * 2);
  __hip_bfloat16* Wt2 = (__hip_bfloat16*)alloc((size_t)Hd * Hd * 2);
  __hip_bfloat16* Wta = (__hip_bfloat16*)alloc((size_t)Hd * Hd * 2);
  __hip_bfloat16* Wlt = (__hip_bfloat16*)alloc((size_t)Hd * On * 2);
  float* aux = (float*)alloc((size_t)5 * Bn * RP * 4);
  float* ssrc1 = aux;
  float* sdst1 = aux + Bn * RP;
  float* ssrc2 = aux + 2 * Bn * RP;
  float* sdst2 = aux + 3 * Bn * RP;
  float* sraw = aux + 4 * Bn * RP;
  __hip_bfloat16* xb = (__hip_bfloat16*)alloc((size_t)Bn * RP * Hd * 2);
  float* xres = (float*)alloc((size_t)Bn * RP * Hd * 4);
  __hip_bfloat16* WhT1 = (__hip_bfloat16*)alloc((size_t)Bn * Hd * RP * 2);
  __hip_bfloat16* WhT2 = (__hip_bfloat16*)alloc((size_t)Bn * Hd * RP * 2);
  __hip_bfloat16* h1b = (__hip_bfloat16*)alloc((size_t)Bn * RP * Hd * 2);
  __hip_bfloat16* h2b = (__hip_bfloat16*)alloc((size_t)Bn * RP * Hd * 2);
  float* h2f = (float*)alloc((size_t)Bn * RP * Hd * 4);

  PrepArgs pa;
  pa.src[0] = W1; pa.src[1] = W2; pa.src[2] = Wa; pa.src[3] = Wl;
  pa.dst[0] = Wt1; pa.dst[1] = Wt2; pa.dst[2] = Wta; pa.dst[3] = Wlt;
  pa.emb = emb; pa.ids = ids; pa.xres = xres; pa.xb = xb; pa.aux = aux;
  prep_kernel<<<6480, 256, 0, stream>>>(pa);

  dim3 ggrid(Bn, Hd / 64);   // 64 x 12
  dim3 agrid(Bn * 12);       // 768 blocks, 64 cols each
  dim3 pgrid(Bn * 3);        // 192 blocks, 256 outs each

  // --- GAT layer 1 ---
  gemm_kernel<0><<<ggrid, 256, 0, stream>>>(xb, Wt1, b1, WhT1, a1, ssrc1, sdst1);
  attf_kernel<1><<<agrid, 256, 0, stream>>>(ssrc1, sdst1, adj, ab1, WhT1,
                                            nullptr, nullptr, h1b);
  // --- GAT layer 2 (+ residual) ---
  gemm_kernel<0><<<ggrid, 256, 0, stream>>>(h1b, Wt2, b2, WhT2, a2, ssrc2, sdst2);
  attf_kernel<2><<<agrid, 256, 0, stream>>>(ssrc2, sdst2, adj, ab2, WhT2, xres,
                                            h2f, h2b);
  // --- pooling scores: sraw = tanh(h2 @ Wa + ba) . v ---
  gemm_kernel<1><<<ggrid, 256, 0, stream>>>(h2b, Wta, ba, nullptr, vv, sraw,
                                            nullptr);
  // --- pool + final linear ---
  poolfinal_kernel<<<pgrid, 256, 0, stream>>>(sraw, h2f, Wlt, bl, out);
}